// Round 10
// baseline (1581.798 us; speedup 1.0000x reference)
//
#include <hip/hip_runtime.h>

typedef unsigned int u32;
typedef unsigned long long u64;
typedef float f32x2 __attribute__((ext_vector_type(2)));

#define NPB 8192
#define BCL 4
#define MS 2048
#define KN 64
#define TOTC (BCL * MS)                       // 8192 centers
#define OFF_POS   (BCL * MS * 128)            // element offsets into d_out (f32)
#define OFF_BATCH (OFF_POS + BCL * MS * 3)
// consumer LDS: tab3 (98304) + s_w (17408) + 2 x group slices (22800) = 161312
// producer LDS: 139296 -- union max = 161312 <= 160 KiB (163840)
#define TAB3_B   98304
#define SW_OFF   98304
#define GRP_OFF  115712
#define GRP_PRIV 22800
#define SMEM_BYTES 161312
#define CONS_BLKS 252                         // 63 blocks/cloud; 4+252 = 256 <= 256 CUs
#define SLOTS 126                             // 63 blocks x 2 groups per cloud
#define NITER 17                              // ceil(2048/126)

__device__ inline u64 umax64(u64 a, u64 b) { return a < b ? b : a; }
__device__ inline u32 umax32(u32 a, u32 b) { return a < b ? b : a; }

// packed f32 ops: IEEE-identical per half to v_add_f32 / v_mul_f32 -> bit-exact
__device__ inline f32x2 pk_add(f32x2 a, f32x2 b) {
  f32x2 d;
  asm("v_pk_add_f32 %0, %1, %2" : "=v"(d) : "v"(a), "v"(b));
  return d;
}
__device__ inline f32x2 pk_mul(f32x2 a, f32x2 b) {
  f32x2 d;
  asm("v_pk_mul_f32 %0, %1, %2" : "=v"(d) : "v"(a), "v"(b));
  return d;
}

// wave64 max via DPP (VALU forwarding, no LDS round-trips).
__device__ inline u32 wave_max_u32(u32 v) {
  v = umax32(v, (u32)__builtin_amdgcn_update_dpp(0, (int)v, 0x111, 0xf, 0xf, false));
  v = umax32(v, (u32)__builtin_amdgcn_update_dpp(0, (int)v, 0x112, 0xf, 0xf, false));
  v = umax32(v, (u32)__builtin_amdgcn_update_dpp(0, (int)v, 0x114, 0xf, 0xf, false));
  v = umax32(v, (u32)__builtin_amdgcn_update_dpp(0, (int)v, 0x118, 0xf, 0xf, false));
  v = umax32(v, (u32)__builtin_amdgcn_update_dpp(0, (int)v, 0x142, 0xa, 0xf, false));
  v = umax32(v, (u32)__builtin_amdgcn_update_dpp(0, (int)v, 0x143, 0xc, 0xf, false));
  return (u32)__builtin_amdgcn_readlane((int)v, 63);
}
// two-phase DPP reduce == lexicographic u64 max over the wave (tie -> min idx)
__device__ inline u64 wave_max_key(u64 lkey) {
  u32 hi = (u32)(lkey >> 32), lo32v = (u32)lkey;
  u32 m = wave_max_u32(hi);
  u32 c = wave_max_u32(hi == m ? lo32v : 0u);
  return ((u64)m << 32) | c;
}

__device__ inline u32 part1by2(u32 x) {   // spread 10 bits -> every 3rd bit
  x &= 0x3ffu;
  x = (x | (x << 16)) & 0x030000FFu;
  x = (x | (x << 8))  & 0x0300F00Fu;
  x = (x | (x << 4))  & 0x030C30C3u;
  x = (x | (x << 2))  & 0x09249249u;
  return x;
}

// Zero the ready flags each launch (graph-replay safe; stream-ordered).
__global__ __launch_bounds__(1024) void init_ready(u32* __restrict__ ready) {
  int i = blockIdx.x * 1024 + threadIdx.x;
  if (i < TOTC) ready[i] = 0u;
}

// ---------------------------------------------------------------------------
// PIPELINE kernel, R10.
// Producer (blocks 0..3): BYTE-IDENTICAL to R8/R9 (absmax 0.0 proven).
// Consumer: CLOUD-PINNED persistent blocks. 252 blocks = 63 per cloud; each
// stages its cloud's pos (96 KB packed f32x3) into LDS ONCE, then its 2
// active 256-thread groups run the byte-faithful R3 scan/sort/MLP per center
// reading pos exclusively from LDS (values round-trip LDS bit-exactly ->
// absmax 0.0). Groups 2,3 idle through barriers (R5-proven). Group (q,g)
// handles m = q*2+g + k*126, k=0..16, clamped to 2047 (duplicate identical
// writes, R6 precedent) -> fixed trip counts, aligned barriers; 256 blocks
// co-resident (1/CU) -> deadlock-free.
// This removes ~786 MB of logical consumer pos reads from L2/fabric -- the
// last testable hypothesis for the producer's +120us in-pipeline penalty
// (R8 falsified vmcnt-drain, R9 falsified poll-RMW/churn) -- and speeds the
// scan phase (LDS latency) shrinking the tail.
// ---------------------------------------------------------------------------
__global__ __launch_bounds__(1024) void pipeline_kernel(
    const float* __restrict__ x, const float* __restrict__ pos,
    u32* __restrict__ ready,
    const float* __restrict__ W1, const float* __restrict__ b1,
    const float* __restrict__ W2, const float* __restrict__ b2,
    const float* __restrict__ W3, const float* __restrict__ b3,
    float* __restrict__ out) {
  __shared__ __align__(16) unsigned char smem_raw[SMEM_BYTES];
  int t = threadIdx.x;

  if (blockIdx.x < BCL) {
    // =================== FPS producer (R8 body, unchanged) =================
    u64* sortb = (u64*)smem_raw;
    float4* tab = (float4*)smem_raw;
    u64* slot = (u64*)(smem_raw + NPB * 16);
    int* s_samp = (int*)(smem_raw + NPB * 16 + 32);

    int b = blockIdx.x, lane = t & 63;
    const float* pb = pos + (size_t)b * NPB * 3;

    // sample 0 is always point 0: post immediately so consumers start now
    if (t == 1) atomicExch(&ready[(size_t)b * MS], 1u);

    // ---- 1) Morton keys (30b) | orig idx (13b) ----
    for (int i = t; i < NPB; i += 1024) {
      float xx = pb[i * 3], yy = pb[i * 3 + 1], zz = pb[i * 3 + 2];
      u32 xi = (u32)fminf(fmaxf(xx * 1024.0f, 0.0f), 1023.0f);
      u32 yi = (u32)fminf(fmaxf(yy * 1024.0f, 0.0f), 1023.0f);
      u32 zi = (u32)fminf(fmaxf(zz * 1024.0f, 0.0f), 1023.0f);
      u32 m = (part1by2(zi) << 2) | (part1by2(yi) << 1) | part1by2(xi);
      sortb[i] = ((u64)m << 13) | (u32)i;
    }
    // ---- 2) bitonic sort 8192 ----
    for (int k = 2; k <= NPB; k <<= 1) {
      for (int j = k >> 1; j > 0; j >>= 1) {
        __syncthreads();
        for (int i = t; i < NPB; i += 1024) {
          int ix = i ^ j;
          if (ix > i) {
            u64 a = sortb[i], c = sortb[ix];
            bool up = ((i & k) == 0);
            if ((a > c) == up) { sortb[i] = c; sortb[ix] = a; }
          }
        }
      }
    }
    __syncthreads();
    // ---- 3) extract my 8-pt blob (Morton-contiguous) ----
    int oi[8];
    #pragma unroll
    for (int i = 0; i < 8; ++i) oi[i] = (int)(sortb[8 * t + i] & 0x1FFFu);
    __syncthreads();               // sort buffer dead; tab may overwrite it

    // ---- 3.5) fill LDS coordinate table (coalesced) + init slots ----
    for (int i = t; i < NPB; i += 1024) {
      float xx = pb[i * 3], yy = pb[i * 3 + 1], zz = pb[i * 3 + 2];
      tab[i] = float4{xx, yy, zz, 0.0f};
    }
    if (t < 3) slot[t] = 0;
    if (t == 0) s_samp[0] = 0;
    __syncthreads();               // tab complete + slots zeroed

    // ---- 4) gather coords + bbox + tie-break lo words; init vs point 0 ----
    f32x2 px[4], py[4], pz[4], mind[4];
    u32 lo[8];
    float bxl = 1e30f, bxh = -1e30f, byl = 1e30f, byh = -1e30f, bzl = 1e30f, bzh = -1e30f;
    #pragma unroll
    for (int j = 0; j < 4; ++j) {
      int iA = oi[2 * j], iB = oi[2 * j + 1];
      float4 A = tab[iA], B = tab[iB];
      px[j] = f32x2{A.x, B.x}; py[j] = f32x2{A.y, B.y}; pz[j] = f32x2{A.z, B.z};
      lo[2 * j] = ~(u32)iA; lo[2 * j + 1] = ~(u32)iB;
      bxl = fminf(bxl, fminf(A.x, B.x)); bxh = fmaxf(bxh, fmaxf(A.x, B.x));
      byl = fminf(byl, fminf(A.y, B.y)); byh = fmaxf(byh, fmaxf(A.y, B.y));
      bzl = fminf(bzl, fminf(A.z, B.z)); bzh = fmaxf(bzh, fmaxf(A.z, B.z));
    }
    u64 lkey = 0, wkey;
    {
      float4 c0 = tab[0];
      f32x2 mcx = f32x2{-c0.x, -c0.x}, mcy = f32x2{-c0.y, -c0.y}, mcz = f32x2{-c0.z, -c0.z};
      #pragma unroll
      for (int j = 0; j < 4; ++j) {
        f32x2 dx = pk_add(px[j], mcx), dy = pk_add(py[j], mcy), dz = pk_add(pz[j], mcz);
        mind[j] = pk_add(pk_add(pk_mul(dx, dx), pk_mul(dy, dy)), pk_mul(dz, dz));
        u64 kA = ((u64)__float_as_uint(mind[j].x) << 32) | lo[2 * j];
        u64 kB = ((u64)__float_as_uint(mind[j].y) << 32) | lo[2 * j + 1];
        lkey = umax64(lkey, umax64(kA, kB));
      }
      wkey = wave_max_key(lkey);
    }

    // ---- 5) sequential loop: ONE raw barrier/iter (no vmcnt drain) ----
    int cur = 0, nxt = 1;
    for (int it = 1; it < MS; ++it) {
      if (lane == 0) atomicMax((u64*)&slot[cur], wkey);
      if (t == 64) slot[nxt] = 0;  // wave 1 zeroes cur_{it+1}
      asm volatile("s_waitcnt lgkmcnt(0)" ::: "memory");
      __builtin_amdgcn_s_barrier();
      __builtin_amdgcn_sched_barrier(0);
      u64 g = slot[cur];           // broadcast read (same addr, no conflict)
      int win = (int)(~(u32)g) & (NPB - 1);
      if (t == 0) s_samp[it] = win;
      // post the sample to consumers: fire-and-forget device-scope atomic
      if (t == 65) atomicExch(&ready[(size_t)b * MS + it], (u32)(win + 1));
      // winner coords: ONE ds_read_b128, same-address broadcast
      float4 wc = tab[win];
      float ncx = wc.x, ncy = wc.y, ncz = wc.z;
      // conservative bbox skip test (bit-exact: only skips provable no-ops)
      float lmax = __uint_as_float((u32)(lkey >> 32));
      float ax = fmaxf(fmaxf(__fsub_rn(bxl, ncx), __fsub_rn(ncx, bxh)), 0.0f);
      float ay = fmaxf(fmaxf(__fsub_rn(byl, ncy), __fsub_rn(ncy, byh)), 0.0f);
      float az = fmaxf(fmaxf(__fsub_rn(bzl, ncz), __fsub_rn(ncz, bzh)), 0.0f);
      float lb2 = (ax * ax + ay * ay + az * az) * 0.9999961853f;  // *(1-2^-18)
      bool upd = (lb2 <= lmax);
      if (__ballot(upd)) {         // wave-uniform branch
        if (upd) {
          f32x2 mcx = f32x2{-ncx, -ncx}, mcy = f32x2{-ncy, -ncy}, mcz = f32x2{-ncz, -ncz};
          u64 acc = 0;
          #pragma unroll
          for (int j = 0; j < 4; ++j) {
            f32x2 dx = pk_add(px[j], mcx), dy = pk_add(py[j], mcy), dz = pk_add(pz[j], mcz);
            f32x2 d2 = pk_add(pk_add(pk_mul(dx, dx), pk_mul(dy, dy)), pk_mul(dz, dz));
            mind[j].x = fminf(mind[j].x, d2.x);
            mind[j].y = fminf(mind[j].y, d2.y);
            u64 kA = ((u64)__float_as_uint(mind[j].x) << 32) | lo[2 * j];
            u64 kB = ((u64)__float_as_uint(mind[j].y) << 32) | lo[2 * j + 1];
            acc = umax64(acc, umax64(kA, kB));
          }
          lkey = acc;
        }
        wkey = wave_max_key(lkey); // all lanes participate (DPP)
      }
      cur = nxt;
      nxt = nxt + 1 == 3 ? 0 : nxt + 1;
    }
    __syncthreads();
    // ---- 6) writeback (coords from LDS table) ----
    float* pos_out = out + OFF_POS + (size_t)b * MS * 3;
    float* batch_out = out + OFF_BATCH + (size_t)b * MS;
    for (int m = t; m < MS; m += 1024) {
      int s = s_samp[m];
      float4 c = tab[s];
      pos_out[m * 3] = c.x;
      pos_out[m * 3 + 1] = c.y;
      pos_out[m * 3 + 2] = c.z;
      batch_out[m] = (float)b;
    }
    return;
  }

  // ====== Cloud-pinned persistent consumer: pos scanned from LDS ============
  {
    int cb = blockIdx.x - BCL;      // 0..251
    int b = cb & (BCL - 1);         // pinned cloud
    int q = cb >> 2;                // 0..62: per-cloud block index
    int g = t >> 8;                 // group 0..3 (2,3 idle through barriers)
    int tl = t & 255;               // local thread id == R3's t
    bool work = (g < 2);
    int slot = q * 2 + (work ? g : 0);   // 0..125
    const float R2CUT = (float)(0.2 * 0.2);   // 0x3D23D70A

    float* tab3 = (float*)smem_raw;                            // 8192 x 3 f32
    float (*s_w)[64] = (float(*)[64])(smem_raw + SW_OFF);      // 68x64 floats
    unsigned char* gb = smem_raw + GRP_OFF + (work ? g : 0) * GRP_PRIV;
    u64* cand = (u64*)gb;                                      // 512 x u64
    int* s_cnt = (int*)(gb + 4096);
    int* s_win = (int*)(gb + 4100);
    float (*s_feat)[68] = (float(*)[68])(gb + 4112);           // 64x68 floats
    float* s_mask       = (float*)(gb + 21520);                // 64 floats
    float (*s_red)[64]  = (float(*)[64])(gb + 21776);          // [4][64]

    // ---- stage this cloud's pos into LDS ONCE (coalesced, bit-exact) ----
    const float* pb = pos + (size_t)b * NPB * 3;
    for (int i = t; i < NPB * 3; i += 1024) tab3[i] = pb[i];
    __syncthreads();

    for (int k = 0; k < NITER; ++k) {
      int m = slot + k * SLOTS;
      if (m >= MS) m = MS - 1;      // clamp: duplicate identical writes, benign
      int c = b * MS + m;           // output center id

      // ---- spin: agent-scope atomic LOAD (no RMW) + sleep ----
      if (work && tl == 0) {
        u32 v;
        while ((v = __hip_atomic_load(&ready[c], __ATOMIC_RELAXED,
                                      __HIP_MEMORY_SCOPE_AGENT)) == 0u)
          __builtin_amdgcn_s_sleep(32);
        *s_win = (int)(v - 1u);
        *s_cnt = 0;
      }
      __syncthreads();
      int s = 0;
      float cx = 0.0f, cy = 0.0f, cz = 0.0f;
      if (work) {
        s = *s_win;
        cx = tab3[s * 3]; cy = tab3[s * 3 + 1]; cz = tab3[s * 3 + 2];
      }

      // ---- Phase 1: radius scan from LDS, R3-exact arithmetic ----
      if (work) {
        for (int j = tl; j < NPB; j += 256) {
          float dx = __fsub_rn(tab3[j * 3], cx);
          float dy = __fsub_rn(tab3[j * 3 + 1], cy);
          float dz = __fsub_rn(tab3[j * 3 + 2], cz);
          float d2 = __fadd_rn(__fadd_rn(__fmul_rn(dx, dx), __fmul_rn(dy, dy)), __fmul_rn(dz, dz));
          if (d2 <= R2CUT) {
            int sl = atomicAdd(s_cnt, 1);
            if (sl < 512) cand[sl] = ((u64)__float_as_uint(d2) << 32) | (u32)j;
          }
        }
      }
      __syncthreads();
      int n = 0;
      if (work) {
        n = *s_cnt; if (n > 512) n = 512;
        for (int i = tl; i < 512; i += 256) if (i >= n) cand[i] = ~0ull;
      }
      __syncthreads();
      for (int kk = 2; kk <= 512; kk <<= 1) {
        for (int j = kk >> 1; j > 0; j >>= 1) {
          if (work) {
            for (int i = tl; i < 512; i += 256) {
              int ix = i ^ j;
              if (ix > i) {
                u64 a = cand[i], bb = cand[ix];
                bool up = ((i & kk) == 0);
                if ((a > bb) == up) { cand[i] = bb; cand[ix] = a; }
              }
            }
          }
          __syncthreads();
        }
      }
      // cand[0..63] = top-K; nbr r = (r<n) ? (int)(cand[r]&0xffffffff) : -1

      // ---- Phase 2: gather -> MLP (in-place) -> masked max-pool ----
      if (work) {
        int r = tl >> 2, qq = tl & 3;
        int j = (r < n) ? (int)(cand[r] & 0xffffffffu) : -1;
        bool valid = (j >= 0 && j < NPB);
        size_t jj = valid ? (size_t)j : 0;
        const float4* xp = (const float4*)(x + ((size_t)b * NPB + jj) * 64 + qq * 16);
        float4 v[4];
        for (int i = 0; i < 4; ++i) v[i] = xp[i];
        for (int i = 0; i < 4; ++i) {
          s_feat[r][qq * 16 + i * 4 + 0] = valid ? v[i].x : 0.0f;
          s_feat[r][qq * 16 + i * 4 + 1] = valid ? v[i].y : 0.0f;
          s_feat[r][qq * 16 + i * 4 + 2] = valid ? v[i].z : 0.0f;
          s_feat[r][qq * 16 + i * 4 + 3] = valid ? v[i].w : 0.0f;
        }
      }
      if (work && tl < 64) {
        int r = tl;
        int j = (r < n) ? (int)(cand[r] & 0xffffffffu) : -1;
        bool valid = (j >= 0 && j < NPB);
        s_mask[r] = valid ? 0.0f : -__builtin_inff();
        size_t jj = valid ? (size_t)j : (size_t)s;
        for (int d = 0; d < 3; ++d) {
          float pj = tab3[jj * 3 + d];   // LDS: bit-identical to pos[...]
          float pc = tab3[(size_t)s * 3 + d];
          s_feat[r][64 + d] = __fsub_rn(pj, pc);
        }
      }
      // W1 load: shared buffer, all 1024 threads (pure copy, exact)
      for (int idx = t; idx < 67 * 64; idx += 1024)
        s_w[idx >> 6][idx & 63] = W1[idx];
      __syncthreads();

      // ---- Layer 1 (reads s_feat 0..66; after barrier writes 0..63) ----
      {
        int r = tl >> 2, n0 = (tl & 3) * 16;
        float acc[16];
        if (work) {
          for (int j = 0; j < 16; ++j) acc[j] = b1[n0 + j];
          for (int kk = 0; kk < 67; ++kk) {
            float f = s_feat[r][kk];
            for (int j = 0; j < 16; ++j) acc[j] += f * s_w[kk][n0 + j];
          }
        }
        __syncthreads();           // ALL reads of s_feat + s_w(W1) complete
        if (work) {
          for (int j = 0; j < 16; ++j) s_feat[r][n0 + j] = fmaxf(acc[j], 0.0f);
        }
        for (int idx = t; idx < 64 * 64; idx += 1024)
          s_w[idx >> 6][idx & 63] = W2[idx];
      }
      __syncthreads();

      // ---- Layer 2 (reads s_feat 0..63 = h1; writes 0..63) ----
      {
        int r = tl >> 2, n0 = (tl & 3) * 16;
        float acc[16];
        if (work) {
          for (int j = 0; j < 16; ++j) acc[j] = b2[n0 + j];
          for (int kk = 0; kk < 64; ++kk) {
            float f = s_feat[r][kk];
            for (int j = 0; j < 16; ++j) acc[j] += f * s_w[kk][n0 + j];
          }
        }
        __syncthreads();           // ALL reads complete
        if (work) {
          for (int j = 0; j < 16; ++j) s_feat[r][n0 + j] = fmaxf(acc[j], 0.0f);
        }
      }
      __syncthreads();

      // ---- Layer 3 (2 halves of 128) + masked max-pool ----
      for (int h = 0; h < 2; ++h) {
        for (int idx = t; idx < 64 * 64; idx += 1024)
          s_w[idx >> 6][idx & 63] = W3[(size_t)(idx >> 6) * 128 + h * 64 + (idx & 63)];
        __syncthreads();
        if (work) {
          int n2 = tl & 63, rg = tl >> 6;
          float acc[16];
          float bias = b3[h * 64 + n2];
          for (int rr = 0; rr < 16; ++rr) acc[rr] = bias;
          for (int kk = 0; kk < 64; ++kk) {
            float w = s_w[kk][n2];
            for (int rr = 0; rr < 16; ++rr) acc[rr] += s_feat[rg * 16 + rr][kk] * w;
          }
          float mm = -__builtin_inff();
          for (int rr = 0; rr < 16; ++rr)
            mm = fmaxf(mm, fmaxf(acc[rr], 0.0f) + s_mask[rg * 16 + rr]);
          s_red[rg][n2] = mm;
        }
        __syncthreads();
        if (work && tl < 64) {
          float mm2 = fmaxf(fmaxf(s_red[0][tl], s_red[1][tl]), fmaxf(s_red[2][tl], s_red[3][tl]));
          out[(size_t)c * 128 + h * 64 + tl] = mm2;
        }
        __syncthreads();
      }
    }
  }
}

// ---------------------------------------------------------------------------
extern "C" void kernel_launch(void* const* d_in, const int* in_sizes, int n_in,
                              void* d_out, int out_size, void* d_ws, size_t ws_size,
                              hipStream_t stream) {
  const float* x   = (const float*)d_in[0];
  const float* pos = (const float*)d_in[1];
  // d_in[2] = batch (int32), unused
  const float* W1 = (const float*)d_in[3];
  const float* b1 = (const float*)d_in[4];
  const float* W2 = (const float*)d_in[5];
  const float* b2 = (const float*)d_in[6];
  const float* W3 = (const float*)d_in[7];
  const float* b3 = (const float*)d_in[8];

  float* out = (float*)d_out;
  u32* ready = (u32*)d_ws;           // [8192] sample-ready flags (win+1)

  init_ready<<<(TOTC + 1023) / 1024, 1024, 0, stream>>>(ready);
  pipeline_kernel<<<BCL + CONS_BLKS, 1024, 0, stream>>>(
      x, pos, ready, W1, b1, W2, b2, W3, b3, out);
}

// Round 11
// 1482.890 us; speedup vs baseline: 1.0667x; 1.0667x over previous
//
#include <hip/hip_runtime.h>

typedef unsigned int u32;
typedef unsigned long long u64;
typedef float f32x2 __attribute__((ext_vector_type(2)));

#define NPB 8192
#define BCL 4
#define MS 2048
#define KN 64
#define TOTC (BCL * MS)                       // 8192 centers
#define OFF_POS   (BCL * MS * 128)            // element offsets into d_out (f32)
#define OFF_BATCH (OFF_POS + BCL * MS * 3)
#define SMEM_BYTES (NPB * 16 + 32 + MS * 4)   // 139296: fps layout (union max)
// consumer LDS carve: shared s_w (17408) + 3 x private group slices (40208)
#define GRP_PRIV 40208
#define CONS_BLKS ((TOTC + 2) / 3)            // 2731

__device__ inline u64 umax64(u64 a, u64 b) { return a < b ? b : a; }
__device__ inline u32 umax32(u32 a, u32 b) { return a < b ? b : a; }

// packed f32 ops: IEEE-identical per half to v_add_f32 / v_mul_f32 -> bit-exact
__device__ inline f32x2 pk_add(f32x2 a, f32x2 b) {
  f32x2 d;
  asm("v_pk_add_f32 %0, %1, %2" : "=v"(d) : "v"(a), "v"(b));
  return d;
}
__device__ inline f32x2 pk_mul(f32x2 a, f32x2 b) {
  f32x2 d;
  asm("v_pk_mul_f32 %0, %1, %2" : "=v"(d) : "v"(a), "v"(b));
  return d;
}

// wave64 max via DPP (VALU forwarding, no LDS round-trips).
__device__ inline u32 wave_max_u32(u32 v) {
  v = umax32(v, (u32)__builtin_amdgcn_update_dpp(0, (int)v, 0x111, 0xf, 0xf, false));
  v = umax32(v, (u32)__builtin_amdgcn_update_dpp(0, (int)v, 0x112, 0xf, 0xf, false));
  v = umax32(v, (u32)__builtin_amdgcn_update_dpp(0, (int)v, 0x114, 0xf, 0xf, false));
  v = umax32(v, (u32)__builtin_amdgcn_update_dpp(0, (int)v, 0x118, 0xf, 0xf, false));
  v = umax32(v, (u32)__builtin_amdgcn_update_dpp(0, (int)v, 0x142, 0xa, 0xf, false));
  v = umax32(v, (u32)__builtin_amdgcn_update_dpp(0, (int)v, 0x143, 0xc, 0xf, false));
  return (u32)__builtin_amdgcn_readlane((int)v, 63);
}
// two-phase DPP reduce == lexicographic u64 max over the wave (tie -> min idx)
__device__ inline u64 wave_max_key(u64 lkey) {
  u32 hi = (u32)(lkey >> 32), lo32v = (u32)lkey;
  u32 m = wave_max_u32(hi);
  u32 c = wave_max_u32(hi == m ? lo32v : 0u);
  return ((u64)m << 32) | c;
}

__device__ inline u32 part1by2(u32 x) {   // spread 10 bits -> every 3rd bit
  x &= 0x3ffu;
  x = (x | (x << 16)) & 0x030000FFu;
  x = (x | (x << 8))  & 0x0300F00Fu;
  x = (x | (x << 4))  & 0x030C30C3u;
  x = (x | (x << 2))  & 0x09249249u;
  return x;
}

// Zero the ready flags each launch (graph-replay safe; stream-ordered).
__global__ __launch_bounds__(1024) void init_ready(u32* __restrict__ ready) {
  int i = blockIdx.x * 1024 + threadIdx.x;
  if (i < TOTC) ready[i] = 0u;
}

// ---------------------------------------------------------------------------
// PIPELINE kernel, R11 = BYTE-EXACT REVERT to R6 (best measured: 1475 us,
// absmax 0.0). Producer (blocks 0..3): R3-proven FPS + fire-and-forget
// atomic posts. Consumer (blocks 4..): THREE R3-exact 256-thread groups per
// block, shared s_w, private slices. All post-R6 experiments (R7 4-slot
// combine, R8 raw barrier + 4-group in-place MLP, R9 persistent blocks +
// load-spin, R10 cloud-pinned LDS-staged consumers) measured neutral or
// negative; every producer-penalty hypothesis (vmcnt drain, poll RMW,
// consumer L2 traffic) was falsified by direct experiment. This restores
// the measured optimum.
// ---------------------------------------------------------------------------
__global__ __launch_bounds__(1024) void pipeline_kernel(
    const float* __restrict__ x, const float* __restrict__ pos,
    u32* __restrict__ ready,
    const float* __restrict__ W1, const float* __restrict__ b1,
    const float* __restrict__ W2, const float* __restrict__ b2,
    const float* __restrict__ W3, const float* __restrict__ b3,
    float* __restrict__ out) {
  __shared__ __align__(16) unsigned char smem_raw[SMEM_BYTES];
  int t = threadIdx.x;

  if (blockIdx.x < BCL) {
    // =================== FPS producer (R3-proven body) =====================
    u64* sortb = (u64*)smem_raw;
    float4* tab = (float4*)smem_raw;
    u64* slot = (u64*)(smem_raw + NPB * 16);
    int* s_samp = (int*)(smem_raw + NPB * 16 + 32);

    int b = blockIdx.x, lane = t & 63;
    const float* pb = pos + (size_t)b * NPB * 3;

    // sample 0 is always point 0: post immediately so consumers start now
    if (t == 1) atomicExch(&ready[(size_t)b * MS], 1u);

    // ---- 1) Morton keys (30b) | orig idx (13b) ----
    for (int i = t; i < NPB; i += 1024) {
      float xx = pb[i * 3], yy = pb[i * 3 + 1], zz = pb[i * 3 + 2];
      u32 xi = (u32)fminf(fmaxf(xx * 1024.0f, 0.0f), 1023.0f);
      u32 yi = (u32)fminf(fmaxf(yy * 1024.0f, 0.0f), 1023.0f);
      u32 zi = (u32)fminf(fmaxf(zz * 1024.0f, 0.0f), 1023.0f);
      u32 m = (part1by2(zi) << 2) | (part1by2(yi) << 1) | part1by2(xi);
      sortb[i] = ((u64)m << 13) | (u32)i;
    }
    // ---- 2) bitonic sort 8192 ----
    for (int k = 2; k <= NPB; k <<= 1) {
      for (int j = k >> 1; j > 0; j >>= 1) {
        __syncthreads();
        for (int i = t; i < NPB; i += 1024) {
          int ix = i ^ j;
          if (ix > i) {
            u64 a = sortb[i], c = sortb[ix];
            bool up = ((i & k) == 0);
            if ((a > c) == up) { sortb[i] = c; sortb[ix] = a; }
          }
        }
      }
    }
    __syncthreads();
    // ---- 3) extract my 8-pt blob (Morton-contiguous) ----
    int oi[8];
    #pragma unroll
    for (int i = 0; i < 8; ++i) oi[i] = (int)(sortb[8 * t + i] & 0x1FFFu);
    __syncthreads();               // sort buffer dead; tab may overwrite it

    // ---- 3.5) fill LDS coordinate table (coalesced) + init slots ----
    for (int i = t; i < NPB; i += 1024) {
      float xx = pb[i * 3], yy = pb[i * 3 + 1], zz = pb[i * 3 + 2];
      tab[i] = float4{xx, yy, zz, 0.0f};
    }
    if (t < 3) slot[t] = 0;
    if (t == 0) s_samp[0] = 0;
    __syncthreads();               // tab complete + slots zeroed

    // ---- 4) gather coords + bbox + tie-break lo words; init vs point 0 ----
    f32x2 px[4], py[4], pz[4], mind[4];
    u32 lo[8];
    float bxl = 1e30f, bxh = -1e30f, byl = 1e30f, byh = -1e30f, bzl = 1e30f, bzh = -1e30f;
    #pragma unroll
    for (int j = 0; j < 4; ++j) {
      int iA = oi[2 * j], iB = oi[2 * j + 1];
      float4 A = tab[iA], B = tab[iB];
      px[j] = f32x2{A.x, B.x}; py[j] = f32x2{A.y, B.y}; pz[j] = f32x2{A.z, B.z};
      lo[2 * j] = ~(u32)iA; lo[2 * j + 1] = ~(u32)iB;
      bxl = fminf(bxl, fminf(A.x, B.x)); bxh = fmaxf(bxh, fmaxf(A.x, B.x));
      byl = fminf(byl, fminf(A.y, B.y)); byh = fmaxf(byh, fmaxf(A.y, B.y));
      bzl = fminf(bzl, fminf(A.z, B.z)); bzh = fmaxf(bzh, fmaxf(A.z, B.z));
    }
    u64 lkey = 0, wkey;
    {
      float4 c0 = tab[0];
      f32x2 mcx = f32x2{-c0.x, -c0.x}, mcy = f32x2{-c0.y, -c0.y}, mcz = f32x2{-c0.z, -c0.z};
      #pragma unroll
      for (int j = 0; j < 4; ++j) {
        f32x2 dx = pk_add(px[j], mcx), dy = pk_add(py[j], mcy), dz = pk_add(pz[j], mcz);
        mind[j] = pk_add(pk_add(pk_mul(dx, dx), pk_mul(dy, dy)), pk_mul(dz, dz));
        u64 kA = ((u64)__float_as_uint(mind[j].x) << 32) | lo[2 * j];
        u64 kB = ((u64)__float_as_uint(mind[j].y) << 32) | lo[2 * j + 1];
        lkey = umax64(lkey, umax64(kA, kB));
      }
      wkey = wave_max_key(lkey);
    }

    // ---- 5) sequential loop: ONE barrier/iter ----
    int cur = 0, nxt = 1;
    for (int it = 1; it < MS; ++it) {
      if (lane == 0) atomicMax((u64*)&slot[cur], wkey);
      if (t == 64) slot[nxt] = 0;  // wave 1 zeroes cur_{it+1}
      __syncthreads();
      u64 g = slot[cur];           // broadcast read (same addr, no conflict)
      int win = (int)(~(u32)g) & (NPB - 1);
      if (t == 0) s_samp[it] = win;
      // post the sample to consumers: fire-and-forget device-scope atomic
      if (t == 65) atomicExch(&ready[(size_t)b * MS + it], (u32)(win + 1));
      // winner coords: ONE ds_read_b128, same-address broadcast
      float4 wc = tab[win];
      float ncx = wc.x, ncy = wc.y, ncz = wc.z;
      // conservative bbox skip test (bit-exact: only skips provable no-ops)
      float lmax = __uint_as_float((u32)(lkey >> 32));
      float ax = fmaxf(fmaxf(__fsub_rn(bxl, ncx), __fsub_rn(ncx, bxh)), 0.0f);
      float ay = fmaxf(fmaxf(__fsub_rn(byl, ncy), __fsub_rn(ncy, byh)), 0.0f);
      float az = fmaxf(fmaxf(__fsub_rn(bzl, ncz), __fsub_rn(ncz, bzh)), 0.0f);
      float lb2 = (ax * ax + ay * ay + az * az) * 0.9999961853f;  // *(1-2^-18)
      bool upd = (lb2 <= lmax);
      if (__ballot(upd)) {         // wave-uniform branch
        if (upd) {
          f32x2 mcx = f32x2{-ncx, -ncx}, mcy = f32x2{-ncy, -ncy}, mcz = f32x2{-ncz, -ncz};
          u64 acc = 0;
          #pragma unroll
          for (int j = 0; j < 4; ++j) {
            f32x2 dx = pk_add(px[j], mcx), dy = pk_add(py[j], mcy), dz = pk_add(pz[j], mcz);
            f32x2 d2 = pk_add(pk_add(pk_mul(dx, dx), pk_mul(dy, dy)), pk_mul(dz, dz));
            mind[j].x = fminf(mind[j].x, d2.x);
            mind[j].y = fminf(mind[j].y, d2.y);
            u64 kA = ((u64)__float_as_uint(mind[j].x) << 32) | lo[2 * j];
            u64 kB = ((u64)__float_as_uint(mind[j].y) << 32) | lo[2 * j + 1];
            acc = umax64(acc, umax64(kA, kB));
          }
          lkey = acc;
        }
        wkey = wave_max_key(lkey); // all lanes participate (DPP)
      }
      cur = nxt;
      nxt = nxt + 1 == 3 ? 0 : nxt + 1;
    }
    __syncthreads();
    // ---- 6) writeback (coords from LDS table) ----
    float* pos_out = out + OFF_POS + (size_t)b * MS * 3;
    float* batch_out = out + OFF_BATCH + (size_t)b * MS;
    for (int m = t; m < MS; m += 1024) {
      int s = s_samp[m];
      float4 c = tab[s];
      pos_out[m * 3] = c.x;
      pos_out[m * 3 + 1] = c.y;
      pos_out[m * 3 + 2] = c.z;
      batch_out[m] = (float)b;
    }
    return;
  }

  // ========== Consumer: 3 R3-exact 256-thread groups per block ==============
  {
    int cblk = blockIdx.x - BCL;
    int g = t >> 8;                 // group 0..3 (group 3 idles)
    int tl = t & 255;               // local thread id == R3's t
    bool work = (g < 3);
    int p = 3 * cblk + (work ? g : 0);
    if (p >= TOTC) p = TOTC - 1;    // duplicate last center: identical writes
    int b = p & (BCL - 1), m = p >> 2;
    int c = b * MS + m;             // output center id
    const float R2CUT = (float)(0.2 * 0.2);   // 0x3D23D70A

    // LDS carve: shared s_w at 0; private group slices after
    float (*s_w)[64] = (float(*)[64])(smem_raw);               // 68x64 floats
    unsigned char* gb = smem_raw + 17408 + (work ? g : 0) * GRP_PRIV;
    u64* cand = (u64*)gb;                                      // 512 x u64
    int* s_cnt = (int*)(gb + 4096);
    int* s_win = (int*)(gb + 4100);
    float (*s_feat)[68] = (float(*)[68])(gb + 4112);
    float (*s_h)[68]    = (float(*)[68])(gb + 21520);
    float* s_mask       = (float*)(gb + 38928);                // 64 floats
    float (*s_red)[64]  = (float(*)[64])(gb + 39184);          // [4][64]

    const float* pb = pos + (size_t)b * NPB * 3;

    // ---- spin until our sample is produced (value travels in the atomic) --
    if (work && tl == 0) {
      u32 v;
      while ((v = atomicAdd(&ready[c], 0u)) == 0u) __builtin_amdgcn_s_sleep(8);
      *s_win = (int)(v - 1u);
      *s_cnt = 0;
    }
    __syncthreads();
    int s = 0;
    float cx = 0.0f, cy = 0.0f, cz = 0.0f;
    if (work) {
      s = *s_win;
      cx = pb[s * 3]; cy = pb[s * 3 + 1]; cz = pb[s * 3 + 2];
    }

    // ---- Phase 1: radius scan, R3-exact (256 threads/group, cap 512) ----
    if (work) {
      for (int j = tl; j < NPB; j += 256) {
        float dx = __fsub_rn(pb[j * 3], cx);
        float dy = __fsub_rn(pb[j * 3 + 1], cy);
        float dz = __fsub_rn(pb[j * 3 + 2], cz);
        float d2 = __fadd_rn(__fadd_rn(__fmul_rn(dx, dx), __fmul_rn(dy, dy)), __fmul_rn(dz, dz));
        if (d2 <= R2CUT) {
          int sl = atomicAdd(s_cnt, 1);
          if (sl < 512) cand[sl] = ((u64)__float_as_uint(d2) << 32) | (u32)j;
        }
      }
    }
    __syncthreads();
    int n = 0;
    if (work) {
      n = *s_cnt; if (n > 512) n = 512;
      for (int i = tl; i < 512; i += 256) if (i >= n) cand[i] = ~0ull;
    }
    __syncthreads();
    for (int k = 2; k <= 512; k <<= 1) {
      for (int j = k >> 1; j > 0; j >>= 1) {
        if (work) {
          for (int i = tl; i < 512; i += 256) {
            int ix = i ^ j;
            if (ix > i) {
              u64 a = cand[i], bb = cand[ix];
              bool up = ((i & k) == 0);
              if ((a > bb) == up) { cand[i] = bb; cand[ix] = a; }
            }
          }
        }
        __syncthreads();
      }
    }
    // cand[0..63] = top-K; neighbor r = (r<n) ? (int)(cand[r]&0xffffffff) : -1

    // ---- Phase 2: gather -> MLP -> masked max-pool, R3-exact per group ----
    if (work) {
      int r = tl >> 2, q = tl & 3;
      int j = (r < n) ? (int)(cand[r] & 0xffffffffu) : -1;
      bool valid = (j >= 0 && j < NPB);
      size_t jj = valid ? (size_t)j : 0;
      const float4* xp = (const float4*)(x + ((size_t)b * NPB + jj) * 64 + q * 16);
      float4 v[4];
      for (int i = 0; i < 4; ++i) v[i] = xp[i];
      for (int i = 0; i < 4; ++i) {
        s_feat[r][q * 16 + i * 4 + 0] = valid ? v[i].x : 0.0f;
        s_feat[r][q * 16 + i * 4 + 1] = valid ? v[i].y : 0.0f;
        s_feat[r][q * 16 + i * 4 + 2] = valid ? v[i].z : 0.0f;
        s_feat[r][q * 16 + i * 4 + 3] = valid ? v[i].w : 0.0f;
      }
    }
    if (work && tl < 64) {
      int r = tl;
      int j = (r < n) ? (int)(cand[r] & 0xffffffffu) : -1;
      bool valid = (j >= 0 && j < NPB);
      s_mask[r] = valid ? 0.0f : -__builtin_inff();
      size_t jj = valid ? (size_t)j : (size_t)s;
      for (int d = 0; d < 3; ++d) {
        float pj = pos[((size_t)b * NPB + jj) * 3 + d];
        float pc = pos[((size_t)b * NPB + s) * 3 + d];
        s_feat[r][64 + d] = __fsub_rn(pj, pc);
      }
    }
    // W1 load: shared buffer, all 1024 threads (pure copy, exact)
    for (int idx = t; idx < 67 * 64; idx += 1024)
      s_w[idx >> 6][idx & 63] = W1[idx];
    __syncthreads();

    {
      int r = tl >> 2, n0 = (tl & 3) * 16;
      float acc[16];
      if (work) {
        for (int j = 0; j < 16; ++j) acc[j] = b1[n0 + j];
        for (int k = 0; k < 67; ++k) {
          float f = s_feat[r][k];
          for (int j = 0; j < 16; ++j) acc[j] += f * s_w[k][n0 + j];
        }
      }
      __syncthreads();             // all groups done reading s_w(W1)
      if (work) {
        for (int j = 0; j < 16; ++j) s_h[r][n0 + j] = fmaxf(acc[j], 0.0f);
      }
      for (int idx = t; idx < 64 * 64; idx += 1024)
        s_w[idx >> 6][idx & 63] = W2[idx];
    }
    __syncthreads();

    {
      int r = tl >> 2, n0 = (tl & 3) * 16;
      float acc[16];
      if (work) {
        for (int j = 0; j < 16; ++j) acc[j] = b2[n0 + j];
        for (int k = 0; k < 64; ++k) {
          float f = s_h[r][k];
          for (int j = 0; j < 16; ++j) acc[j] += f * s_w[k][n0 + j];
        }
      }
      __syncthreads();             // all groups done reading s_w(W2)
      if (work) {
        for (int j = 0; j < 16; ++j) s_feat[r][n0 + j] = fmaxf(acc[j], 0.0f);
      }
    }
    __syncthreads();

    for (int h = 0; h < 2; ++h) {
      for (int idx = t; idx < 64 * 64; idx += 1024)
        s_w[idx >> 6][idx & 63] = W3[(size_t)(idx >> 6) * 128 + h * 64 + (idx & 63)];
      __syncthreads();
      if (work) {
        int n2 = tl & 63, rg = tl >> 6;
        float acc[16];
        float bias = b3[h * 64 + n2];
        for (int rr = 0; rr < 16; ++rr) acc[rr] = bias;
        for (int k = 0; k < 64; ++k) {
          float w = s_w[k][n2];
          for (int rr = 0; rr < 16; ++rr) acc[rr] += s_feat[rg * 16 + rr][k] * w;
        }
        float mm = -__builtin_inff();
        for (int rr = 0; rr < 16; ++rr)
          mm = fmaxf(mm, fmaxf(acc[rr], 0.0f) + s_mask[rg * 16 + rr]);
        s_red[rg][n2] = mm;
      }
      __syncthreads();
      if (work && tl < 64) {
        float mm = fmaxf(fmaxf(s_red[0][tl], s_red[1][tl]), fmaxf(s_red[2][tl], s_red[3][tl]));
        out[(size_t)c * 128 + h * 64 + tl] = mm;
      }
      __syncthreads();
    }
  }
}

// ---------------------------------------------------------------------------
extern "C" void kernel_launch(void* const* d_in, const int* in_sizes, int n_in,
                              void* d_out, int out_size, void* d_ws, size_t ws_size,
                              hipStream_t stream) {
  const float* x   = (const float*)d_in[0];
  const float* pos = (const float*)d_in[1];
  // d_in[2] = batch (int32), unused
  const float* W1 = (const float*)d_in[3];
  const float* b1 = (const float*)d_in[4];
  const float* W2 = (const float*)d_in[5];
  const float* b2 = (const float*)d_in[6];
  const float* W3 = (const float*)d_in[7];
  const float* b3 = (const float*)d_in[8];

  float* out = (float*)d_out;
  u32* ready = (u32*)d_ws;           // [8192] sample-ready flags (win+1)

  init_ready<<<(TOTC + 1023) / 1024, 1024, 0, stream>>>(ready);
  pipeline_kernel<<<BCL + CONS_BLKS, 1024, 0, stream>>>(
      x, pos, ready, W1, b1, W2, b2, W3, b3, out);
}